// Round 1
// baseline (153.467 us; speedup 1.0000x reference)
//
#include <hip/hip_runtime.h>
#include <cstdint>

#pragma clang fp contract(off)

#define NB      32
#define NC      18
#define NA      8400
#define NCH     (4 + NC)
#define NTASK   (NB * NC)      // 576
#define TOPK    300
#define TARGET  316        // TOPK + margin: absorbs sigmoid-tie rank ambiguity
#define NBINS   2048
#define CAP     1024
#define CONF    0.25f
#define IOU_T   0.45f
#define NT      512
#define NW      (NT / 64)
// Prefilter: N(0,1) logits, top-316 cutoff ~1.75 +- 0.1; count(x>1.4) in [553,803] (5-sigma).
// Fast path requires TARGET <= s_cnt <= CAP, else exact fallback.
#define PREF_X  1.4f
// sigmoid(x) > 0.25  <=>  x > -ln(3). Outside [XLO,XHI] analytic compare is exact.
#define XHI     (-1.0984f)
#define XLO     (-1.0988f)

// Fast-path binning: keys (mono_key of x>1.4) start at 0xBFB33333.
#define FAST_KBASE 0xBFB00000u
#define FAST_SHIFT 14
// Fallback binning: conf_pass keys start ~0x40735C26.
#define FB_KBASE   0x40000000u
#define FB_SHIFT   21

// Exact div-free IoU compare: RN_f32(inter/D) > 0.45f  <=>  inter > M45*D.
// M45 = fp32(0.45) + 2^-26 (25-bit mantissa, exact in f64; x 24-bit D -> exact
// 49-bit product). Tie rounds-to-even back to 0.45f => not >, matching. Bit-exact.
#define M45 (30198989.0 / 67108864.0)

typedef unsigned long long ull;

__device__ __forceinline__ float sigmoidf(float x) {
    return 1.0f / (1.0f + expf(-x));
}
__device__ __forceinline__ unsigned int mono_key(unsigned int bits) {
    return (bits & 0x80000000u) ? ~bits : (bits | 0x80000000u);
}
__device__ __forceinline__ unsigned int mono_inv(unsigned int key) {
    return (key & 0x80000000u) ? (key ^ 0x80000000u) : ~key;
}
__device__ __forceinline__ bool conf_pass(float x) {
    if (x >= XHI) return true;
    if (x <= XLO) return false;
    return sigmoidf(x) > CONF;   // rare exact band (~1 element per task)
}
__device__ __forceinline__ unsigned int make_key(float x) {
    return conf_pass(x) ? mono_key(__float_as_uint(x)) : 0u;
}
__device__ __forceinline__ ull readlane64(ull v, int i) {
    unsigned lo = (unsigned)__builtin_amdgcn_readlane((int)(unsigned)(v & 0xFFFFFFFFull), i);
    unsigned hi = (unsigned)__builtin_amdgcn_readlane((int)(unsigned)(v >> 32), i);
    return ((ull)hi << 32) | (ull)lo;
}

// Suffix-find over hist: T1 s.t. count(bins > T1) < target <= count(bins >= T1).
__device__ __forceinline__ void suffix_find(unsigned int* hist, unsigned int* wtot,
                                            int target, int tid, int* s_T1) {
    const int base = tid * (NBINS / NT);
    unsigned int v = 0;
#pragma unroll
    for (int k = 0; k < NBINS / NT; ++k) v += hist[base + k];
    const int lane = tid & 63;
    unsigned int s = v;
#pragma unroll
    for (int d = 1; d < 64; d <<= 1) {
        unsigned int o = __shfl_down(s, d, 64);
        if (lane + d < 64) s += o;
    }
    if (lane == 0) wtot[tid >> 6] = s;
    __syncthreads();
    unsigned int above_waves = 0;
    for (int wv = (tid >> 6) + 1; wv < NW; ++wv) above_waves += wtot[wv];
    unsigned int acc = (s - v) + above_waves;
    for (int bin = base + (NBINS / NT) - 1; bin >= base; --bin) {
        unsigned int cnt = hist[bin];
        if (acc < (unsigned int)target && acc + cnt >= (unsigned int)target) *s_T1 = bin;
        acc += cnt;
    }
    __syncthreads();
}

// Pool layout: [0,8192) hist -> cand2 -> sSup(12000B, also spills into cand region)
// [8192,16384) cand. All reuses are barrier-separated.
#define OFF_CAND   8192
#define POOL1_BYTES 16384

// PIN: keep LDS-loaded mask words in VGPRs across the serial scan. R12 of the
// previous session showed the compiler otherwise rematerializes the loads
// inside the scan loop; post-asm the values are opaque -> must stay resident.
#define PIN64(x) asm volatile("" : "+v"(x))

// ============ Fused: select -> mask -> greedy scan -> output. One block per
// task; all intermediates (top-300 boxes/vals, 300x5 suppression words) live
// in LDS. Eliminates the wsBox/wsVal/wsSup HBM round-trips (~17 MB) and two
// dependent kernel launches of the 3-kernel pipeline. ============
__global__ __launch_bounds__(NT, 4) void k_fused(const float* __restrict__ in,
                                                 float* __restrict__ out) {
    __shared__ __align__(16) unsigned char pool[POOL1_BYTES];
    __shared__ __align__(16) float4 sBox[TOPK];
    __shared__ float sVal[TOPK];
    __shared__ float sAr[TOPK];
    __shared__ unsigned int wtot[NW];
    __shared__ unsigned int s_cnt, s_cnt2;
    __shared__ int s_T1;

    unsigned int* hist = (unsigned int*)pool;
    ull* cand2 = (ull*)pool;
    ull* cand  = (ull*)(pool + OFF_CAND);
    ull* sSup  = (ull*)pool;              // valid after rank phase barrier

    const int tid = threadIdx.x;
    const int lane = tid & 63;
    const int wave = tid >> 6;
    const ull ltm = (1ull << lane) - 1ull;
    const int t = blockIdx.x;
    // XCD swizzle: image b -> XCD b%8
    const int b = (t & 7) + 8 * ((t >> 3) & 3);
    const int c = t >> 5;
    const float* cls = in + (size_t)b * NCH * NA + (size_t)(4 + c) * NA;
    const float* box = in + (size_t)b * NCH * NA;

    for (int i = tid; i < NBINS; i += NT) hist[i] = 0;
    // zero rows that select may leave unwritten (rank >= numSel)
    for (int r = tid; r < TOPK; r += NT) {
        sBox[r] = float4{0.f, 0.f, 0.f, 0.f};
        sVal[r] = 0.f;
    }
    if (tid == 0) { s_cnt = 0; s_cnt2 = 0; s_T1 = -1; }
    __syncthreads();

    // P1: prefilter x>1.4, wave-aggregated compaction, fused refine histogram
    {
        const float4* cls4 = (const float4*)cls;
        for (int q = tid; q < NA / 4; q += NT) {
            float4 v = cls4[q];
            const unsigned int i0 = (unsigned int)q * 4u;
            float xs[4] = {v.x, v.y, v.z, v.w};
            ull m[4];
            unsigned int cnt = 0;
#pragma unroll
            for (int u = 0; u < 4; ++u) {
                m[u] = __ballot(xs[u] > PREF_X);
                cnt += (unsigned int)__popcll(m[u]);
            }
            if (cnt) {
                unsigned int base = 0;
                if (lane == 0) base = atomicAdd(&s_cnt, cnt);
                base = (unsigned int)__builtin_amdgcn_readfirstlane((int)base);
                unsigned int pre = 0;
#pragma unroll
                for (int u = 0; u < 4; ++u) {
                    if (xs[u] > PREF_X) {
                        unsigned int mk = mono_key(__float_as_uint(xs[u]));
                        atomicAdd(&hist[min((mk - FAST_KBASE) >> FAST_SHIFT,
                                            (unsigned)(NBINS - 1))], 1u);
                        unsigned int p = base + pre + (unsigned int)__popcll(m[u] & ltm);
                        if (p < CAP)
                            cand[p] = ((ull)mk << 32) | (ull)(~(i0 + u));
                    }
                    pre += (unsigned int)__popcll(m[u]);
                }
            }
        }
    }
    __syncthreads();

    const int pcnt = (int)s_cnt;
    if (pcnt >= TARGET && pcnt <= CAP) {
        // ---- fast path ----
        suffix_find(hist, wtot, TARGET, tid, &s_T1);
        const ull thr = ((ull)FAST_KBASE + ((ull)(unsigned int)s_T1 << FAST_SHIFT)) << 32;
        const int iters = (pcnt + NT - 1) / NT;
        for (int it = 0; it < iters; ++it) {
            int e = tid + it * NT;
            bool act = e < pcnt;
            ull k = act ? cand[e] : 0ull;
            bool sel = act && (k >= thr);
            ull mb = __ballot(sel);
            unsigned int cnt = (unsigned int)__popcll(mb);
            if (cnt) {
                unsigned int basep = 0;
                if (lane == 0) basep = atomicAdd(&s_cnt2, cnt);
                basep = (unsigned int)__builtin_amdgcn_readfirstlane((int)basep);
                if (sel) {
                    float xv = __uint_as_float(mono_inv((unsigned int)(k >> 32)));
                    float sv = sigmoidf(xv);
                    unsigned int p = basep + (unsigned int)__popcll(mb & ltm);
                    if (p < CAP)
                        cand2[p] = ((ull)__float_as_uint(sv) << 32) | (k & 0xFFFFFFFFull);
                }
            }
        }
        __syncthreads();
    } else {
        // ---- exact fallback (rare): re-zero hist, full conf_pass histogram ----
        __syncthreads();
        for (int i = tid; i < NBINS; i += NT) hist[i] = 0;
        __syncthreads();
        {
            const float4* cls4 = (const float4*)cls;
            for (int q = tid; q < NA / 4; q += NT) {
                float4 v = cls4[q];
                unsigned int kx = make_key(v.x), ky = make_key(v.y);
                unsigned int kz = make_key(v.z), kw = make_key(v.w);
                if (kx) atomicAdd(&hist[min((kx - FB_KBASE) >> FB_SHIFT, (unsigned)(NBINS - 1))], 1u);
                if (ky) atomicAdd(&hist[min((ky - FB_KBASE) >> FB_SHIFT, (unsigned)(NBINS - 1))], 1u);
                if (kz) atomicAdd(&hist[min((kz - FB_KBASE) >> FB_SHIFT, (unsigned)(NBINS - 1))], 1u);
                if (kw) atomicAdd(&hist[min((kw - FB_KBASE) >> FB_SHIFT, (unsigned)(NBINS - 1))], 1u);
            }
        }
        __syncthreads();
        suffix_find(hist, wtot, TARGET, tid, &s_T1);
        {
            const ull thr = (s_T1 < 0) ? 0ull
                : ((ull)FB_KBASE + ((ull)(unsigned int)s_T1 << FB_SHIFT));
            const float4* cls4 = (const float4*)cls;
            for (int q = tid; q < NA / 4; q += NT) {
                float4 v = cls4[q];
                const unsigned int i0 = (unsigned int)q * 4u;
                float xs[4] = {v.x, v.y, v.z, v.w};
#pragma unroll
                for (int u = 0; u < 4; ++u) {
                    unsigned int d = make_key(xs[u]);
                    if (d && (ull)d >= thr) {
                        unsigned int p = atomicAdd(&s_cnt2, 1u);
                        if (p < CAP) {
                            float sv = sigmoidf(xs[u]);
                            cand2[p] = ((ull)__float_as_uint(sv) << 32) | (ull)(~(i0 + u));
                        }
                    }
                }
            }
        }
        __syncthreads();
    }

    const int F = min((int)s_cnt2, CAP);
    const int numSel = min(F, TOPK);

    // rank-by-counting (unique keys via ~idx) + FUSED box gather -> LDS
    for (int e = tid; e < F; e += NT) {
        ull k = cand2[e];
        int rank = 0;
        int o = 0;
#pragma unroll 2
        for (; o + 4 <= F; o += 4) {
            ulonglong2 p0 = *(const ulonglong2*)&cand2[o];
            ulonglong2 p1 = *(const ulonglong2*)&cand2[o + 2];
            rank += (p0.x > k) + (p0.y > k) + (p1.x > k) + (p1.y > k);
        }
        for (; o < F; ++o) rank += (cand2[o] > k) ? 1 : 0;
        if (rank < TOPK) {
            unsigned int i = ~(unsigned int)(k & 0xFFFFFFFFull);
            float cx = box[i];
            float cy = box[NA + i];
            float w  = box[2 * NA + i];
            float h  = box[3 * NA + i];
            float hw = w * 0.5f, hh = h * 0.5f;
            sBox[rank] = float4{cx - hw, cy - hh, cx + hw, cy + hh};
            sVal[rank] = __uint_as_float((unsigned int)(k >> 32));
        }
    }
    __syncthreads();   // cand2 dead from here; pool becomes sSup

    // areas
    for (int r = tid; r < TOPK; r += NT) {
        float4 v = sBox[r];
        sAr[r] = fmaxf(v.z - v.x, 0.f) * fmaxf(v.w - v.y, 0.f);
    }
    __syncthreads();

    // ---- suppression-mask build: rows striped across the 8 waves ----
    float4 cb[5];
    float ca[5];
#pragma unroll
    for (int w = 0; w < 5; ++w) {
        int j = (w << 6) + lane;
        bool v = j < TOPK;
        cb[w] = v ? sBox[j] : float4{0.f, 0.f, 0.f, 0.f};
        ca[w] = v ? sAr[j] : 0.f;
    }
    for (int r = wave; r < TOPK; r += NW) {
        const bool vrow = r < numSel;      // wave-uniform
        const int w0 = r >> 6;             // words < w0 have all columns <= r
        float4 bi = sBox[r];
        float ai = sAr[r];
#pragma unroll
        for (int w = 0; w < 5; ++w) {
            ull bal = 0ull;
            if (w >= w0 && vrow) {         // uniform branch
                const int j = (w << 6) + lane;
                bool supb = false;
                if (j < numSel && j > r) {
                    float xx1 = fmaxf(bi.x, cb[w].x);
                    float yy1 = fmaxf(bi.y, cb[w].y);
                    float xx2 = fminf(bi.z, cb[w].z);
                    float yy2 = fminf(bi.w, cb[w].w);
                    float iw = fmaxf(xx2 - xx1, 0.0f);
                    float ih = fmaxf(yy2 - yy1, 0.0f);
                    float inter = iw * ih;
                    float un = ai + ca[w] - inter;
                    float D = fmaxf(un, 1e-9f);
                    supb = (double)inter > M45 * (double)D;  // == RN(inter/D) > 0.45f
                }
                bal = __ballot(supb);
            }
            if (lane == 0) sSup[r * 5 + w] = bal;
        }
    }
    __syncthreads();

    // ---- greedy scan (wave 0 only; waves 1-7 retire, freeing issue slots) ----
    if (wave != 0) return;

    ull rem0 = 0, rem1 = 0, rem2 = 0, rem3 = 0, rem4 = 0;
    {
        const ull* p = sSup + (size_t)lane * 5;
        ull B0 = p[0], B1 = p[1], B2 = p[2], B3 = p[3], B4 = p[4];
        PIN64(B0); PIN64(B1); PIN64(B2); PIN64(B3); PIN64(B4);
        int n = min(numSel, 64);
        for (int i = 0; i < n; ++i)
            if (!((rem0 >> i) & 1ull)) {    // uniform: rem identical on all lanes
                rem0 |= readlane64(B0, i); rem1 |= readlane64(B1, i);
                rem2 |= readlane64(B2, i); rem3 |= readlane64(B3, i);
                rem4 |= readlane64(B4, i);
            }
    }
    {
        const ull* p = sSup + (size_t)(64 + lane) * 5;
        ull B0 = p[0], B1 = p[1], B2 = p[2], B3 = p[3], B4 = p[4];
        PIN64(B0); PIN64(B1); PIN64(B2); PIN64(B3); PIN64(B4);
        int n = min(max(numSel - 64, 0), 64);
        for (int i = 0; i < n; ++i)
            if (!((rem1 >> i) & 1ull)) {
                rem0 |= readlane64(B0, i); rem1 |= readlane64(B1, i);
                rem2 |= readlane64(B2, i); rem3 |= readlane64(B3, i);
                rem4 |= readlane64(B4, i);
            }
    }
    {
        const ull* p = sSup + (size_t)(128 + lane) * 5;
        ull B0 = p[0], B1 = p[1], B2 = p[2], B3 = p[3], B4 = p[4];
        PIN64(B0); PIN64(B1); PIN64(B2); PIN64(B3); PIN64(B4);
        int n = min(max(numSel - 128, 0), 64);
        for (int i = 0; i < n; ++i)
            if (!((rem2 >> i) & 1ull)) {
                rem0 |= readlane64(B0, i); rem1 |= readlane64(B1, i);
                rem2 |= readlane64(B2, i); rem3 |= readlane64(B3, i);
                rem4 |= readlane64(B4, i);
            }
    }
    {
        const ull* p = sSup + (size_t)(192 + lane) * 5;
        ull B0 = p[0], B1 = p[1], B2 = p[2], B3 = p[3], B4 = p[4];
        PIN64(B0); PIN64(B1); PIN64(B2); PIN64(B3); PIN64(B4);
        int n = min(max(numSel - 192, 0), 64);
        for (int i = 0; i < n; ++i)
            if (!((rem3 >> i) & 1ull)) {
                rem0 |= readlane64(B0, i); rem1 |= readlane64(B1, i);
                rem2 |= readlane64(B2, i); rem3 |= readlane64(B3, i);
                rem4 |= readlane64(B4, i);
            }
    }
    {
        const bool v4 = lane < (TOPK - 256);
        const ull* p = sSup + (size_t)(256 + (v4 ? lane : 0)) * 5;
        ull B0 = v4 ? p[0] : 0ull, B1 = v4 ? p[1] : 0ull, B2 = v4 ? p[2] : 0ull,
            B3 = v4 ? p[3] : 0ull, B4 = v4 ? p[4] : 0ull;
        PIN64(B0); PIN64(B1); PIN64(B2); PIN64(B3); PIN64(B4);
        int n = min(max(numSel - 256, 0), 64);
        for (int i = 0; i < n; ++i)
            if (!((rem4 >> i) & 1ull)) {
                rem0 |= readlane64(B0, i); rem1 |= readlane64(B1, i);
                rem2 |= readlane64(B2, i); rem3 |= readlane64(B3, i);
                rem4 |= readlane64(B4, i);
            }
    }

    float* outp = out + ((size_t)b * NC + c) * (TOPK * 6);
    auto write_row = [&](int w, ull remw) {
        int r = (w << 6) + lane;
        if (r < TOPK) {
            float x1 = 0.f, y1 = 0.f, x2 = 0.f, y2 = 0.f, vv = 0.f, cc = 0.f;
            if (r < numSel && ((~remw >> lane) & 1ull)) {
                float4 bb = sBox[r];
                x1 = bb.x; y1 = bb.y; x2 = bb.z; y2 = bb.w;
                vv = sVal[r]; cc = (float)c;
            }
            float* row = outp + r * 6;
            *(float2*)(row)     = float2{x1, y1};
            *(float2*)(row + 2) = float2{x2, y2};
            *(float2*)(row + 4) = float2{vv, cc};
        }
    };
    write_row(0, rem0);
    write_row(1, rem1);
    write_row(2, rem2);
    write_row(3, rem3);
    write_row(4, rem4);
}

extern "C" void kernel_launch(void* const* d_in, const int* in_sizes, int n_in,
                              void* d_out, int out_size, void* d_ws, size_t ws_size,
                              hipStream_t stream) {
    const float* in = (const float*)d_in[0];
    float* out = (float*)d_out;
    (void)d_ws; (void)ws_size;   // fused kernel keeps all intermediates in LDS

    k_fused<<<NTASK, NT, 0, stream>>>(in, out);
}

// Round 2
// 102.137 us; speedup vs baseline: 1.5026x; 1.5026x over previous
//
#include <hip/hip_runtime.h>
#include <cstdint>

#pragma clang fp contract(off)

#define NB      32
#define NC      18
#define NA      8400
#define NCH     (4 + NC)
#define NTASK   (NB * NC)      // 576
#define TOPK    300
#define TARGET  316        // TOPK + margin: absorbs sigmoid-tie rank ambiguity
#define NBINS   2048
#define CAP     1024
#define CONF    0.25f
#define IOU_T   0.45f
#define NT      512
#define NW      (NT / 64)
// Prefilter: N(0,1) logits, top-316 cutoff ~1.75 +- 0.1; count(x>1.4) in [553,803] (5-sigma).
// Fast path requires TARGET <= s_cnt <= CAP, else exact fallback.
#define PREF_X  1.4f
// sigmoid(x) > 0.25  <=>  x > -ln(3). Outside [XLO,XHI] analytic compare is exact.
#define XHI     (-1.0984f)
#define XLO     (-1.0988f)

// Fast-path binning: keys (mono_key of x>1.4) start at 0xBFB33333.
#define FAST_KBASE 0xBFB00000u
#define FAST_SHIFT 14
// Fallback binning: conf_pass keys start ~0x40735C26.
#define FB_KBASE   0x40000000u
#define FB_SHIFT   21

// Exact div-free IoU compare: RN_f32(inter/D) > 0.45f  <=>  inter > M45*D.
// M45 = fp32(0.45) + 2^-26 (25-bit mantissa, exact in f64; x 24-bit D -> exact
// 49-bit product). Tie rounds-to-even back to 0.45f => not >, matching. Bit-exact.
#define M45 (30198989.0 / 67108864.0)

typedef unsigned long long ull;

__device__ __forceinline__ float sigmoidf(float x) {
    return 1.0f / (1.0f + expf(-x));
}
__device__ __forceinline__ unsigned int mono_key(unsigned int bits) {
    return (bits & 0x80000000u) ? ~bits : (bits | 0x80000000u);
}
__device__ __forceinline__ unsigned int mono_inv(unsigned int key) {
    return (key & 0x80000000u) ? (key ^ 0x80000000u) : ~key;
}
__device__ __forceinline__ bool conf_pass(float x) {
    if (x >= XHI) return true;
    if (x <= XLO) return false;
    return sigmoidf(x) > CONF;   // rare exact band (~1 element per task)
}
__device__ __forceinline__ unsigned int make_key(float x) {
    return conf_pass(x) ? mono_key(__float_as_uint(x)) : 0u;
}
__device__ __forceinline__ ull readlane64(ull v, int i) {
    unsigned lo = (unsigned)__builtin_amdgcn_readlane((int)(unsigned)(v & 0xFFFFFFFFull), i);
    unsigned hi = (unsigned)__builtin_amdgcn_readlane((int)(unsigned)(v >> 32), i);
    return ((ull)hi << 32) | (ull)lo;
}

// Suffix-find over hist: T1 s.t. count(bins > T1) < target <= count(bins >= T1).
__device__ __forceinline__ void suffix_find(unsigned int* hist, unsigned int* wtot,
                                            int target, int tid, int* s_T1) {
    const int base = tid * (NBINS / NT);
    unsigned int v = 0;
#pragma unroll
    for (int k = 0; k < NBINS / NT; ++k) v += hist[base + k];
    const int lane = tid & 63;
    unsigned int s = v;
#pragma unroll
    for (int d = 1; d < 64; d <<= 1) {
        unsigned int o = __shfl_down(s, d, 64);
        if (lane + d < 64) s += o;
    }
    if (lane == 0) wtot[tid >> 6] = s;
    __syncthreads();
    unsigned int above_waves = 0;
    for (int wv = (tid >> 6) + 1; wv < NW; ++wv) above_waves += wtot[wv];
    unsigned int acc = (s - v) + above_waves;
    for (int bin = base + (NBINS / NT) - 1; bin >= base; --bin) {
        unsigned int cnt = hist[bin];
        if (acc < (unsigned int)target && acc + cnt >= (unsigned int)target) *s_T1 = bin;
        acc += cnt;
    }
    __syncthreads();
}

// Pool layout: [0,8192) hist -> cand2 -> sSup(12000B, spills into cand region)
// [8192,16384) cand. All reuses are barrier-separated.
#define OFF_CAND   8192
#define POOL1_BYTES 16384

// PIN: keep loaded mask words in VGPRs across the serial scan (compiler
// otherwise rematerializes the loads inside the scan loop).
#define PIN64(x) asm volatile("" : "+v"(x))

// ============ Fused: select -> mask -> greedy scan -> output. One block per
// task; all intermediates in LDS.
// Key data fact exploited below: boxes are raw N(0,1) outputs -> only ~25%
// have w>0 && h>0. area_i == 0.0f  =>  inter(i,j) == 0.0f exactly for all j
// (RN monotone: inter_x <= clip(w), inter_y <= clip(h), product <= area = 0,
// and >= 0). So zero-area rows have all-zero mask rows and can be skipped in
// BOTH the mask build (~4x less IoU work) and the serial greedy scan
// (ctz over a nonzero-row ballot instead of 300 dependent iterations). ============
__global__ __launch_bounds__(NT, 4) void k_fused(const float* __restrict__ in,
                                                 float* __restrict__ out) {
    __shared__ __align__(16) unsigned char pool[POOL1_BYTES];
    __shared__ __align__(16) float4 sBox[TOPK];
    __shared__ float sVal[TOPK];
    __shared__ float sAr[TOPK];
    __shared__ unsigned int wtot[NW];
    __shared__ unsigned int s_cnt, s_cnt2;
    __shared__ int s_T1;

    unsigned int* hist = (unsigned int*)pool;
    ull* cand2 = (ull*)pool;
    ull* cand  = (ull*)(pool + OFF_CAND);
    ull* sSup  = (ull*)pool;              // valid after rank phase barrier

    const int tid = threadIdx.x;
    const int lane = tid & 63;
    const int wave = tid >> 6;
    const ull ltm = (1ull << lane) - 1ull;
    const int t = blockIdx.x;
    // XCD swizzle: image b -> XCD b%8
    const int b = (t & 7) + 8 * ((t >> 3) & 3);
    const int c = t >> 5;
    const float* cls = in + (size_t)b * NCH * NA + (size_t)(4 + c) * NA;
    const float* box = in + (size_t)b * NCH * NA;

    for (int i = tid; i < NBINS; i += NT) hist[i] = 0;
    // zero rows that select may leave unwritten (rank >= numSel)
    for (int r = tid; r < TOPK; r += NT) {
        sBox[r] = float4{0.f, 0.f, 0.f, 0.f};
        sVal[r] = 0.f;
        sAr[r] = 0.f;
    }
    if (tid == 0) { s_cnt = 0; s_cnt2 = 0; s_T1 = -1; }
    __syncthreads();

    // P1: prefilter x>1.4, wave-aggregated compaction, fused refine histogram.
    // 2-deep software prefetch: next iteration's load issues before this
    // iteration's ballot/atomic section (hides ~600cy global latency).
    {
        const float4* cls4 = (const float4*)cls;
        int q = tid;                       // tid < NT <= NA/4: first load valid
        float4 v = cls4[q];
        while (true) {
            const int qn = q + NT;
            const bool more = qn < NA / 4;
            float4 vn;
            if (more) vn = cls4[qn];

            const unsigned int i0 = (unsigned int)q * 4u;
            float xs[4] = {v.x, v.y, v.z, v.w};
            ull m[4];
            unsigned int cnt = 0;
#pragma unroll
            for (int u = 0; u < 4; ++u) {
                m[u] = __ballot(xs[u] > PREF_X);
                cnt += (unsigned int)__popcll(m[u]);
            }
            if (cnt) {
                unsigned int base = 0;
                if (lane == 0) base = atomicAdd(&s_cnt, cnt);
                base = (unsigned int)__builtin_amdgcn_readfirstlane((int)base);
                unsigned int pre = 0;
#pragma unroll
                for (int u = 0; u < 4; ++u) {
                    if (xs[u] > PREF_X) {
                        unsigned int mk = mono_key(__float_as_uint(xs[u]));
                        atomicAdd(&hist[min((mk - FAST_KBASE) >> FAST_SHIFT,
                                            (unsigned)(NBINS - 1))], 1u);
                        unsigned int p = base + pre + (unsigned int)__popcll(m[u] & ltm);
                        if (p < CAP)
                            cand[p] = ((ull)mk << 32) | (ull)(~(i0 + u));
                    }
                    pre += (unsigned int)__popcll(m[u]);
                }
            }
            if (!more) break;
            v = vn; q = qn;
        }
    }
    __syncthreads();

    const int pcnt = (int)s_cnt;
    if (pcnt >= TARGET && pcnt <= CAP) {
        // ---- fast path ----
        suffix_find(hist, wtot, TARGET, tid, &s_T1);
        const ull thr = ((ull)FAST_KBASE + ((ull)(unsigned int)s_T1 << FAST_SHIFT)) << 32;
        const int iters = (pcnt + NT - 1) / NT;
        for (int it = 0; it < iters; ++it) {
            int e = tid + it * NT;
            bool act = e < pcnt;
            ull k = act ? cand[e] : 0ull;
            bool sel = act && (k >= thr);
            ull mb = __ballot(sel);
            unsigned int cnt = (unsigned int)__popcll(mb);
            if (cnt) {
                unsigned int basep = 0;
                if (lane == 0) basep = atomicAdd(&s_cnt2, cnt);
                basep = (unsigned int)__builtin_amdgcn_readfirstlane((int)basep);
                if (sel) {
                    float xv = __uint_as_float(mono_inv((unsigned int)(k >> 32)));
                    float sv = sigmoidf(xv);
                    unsigned int p = basep + (unsigned int)__popcll(mb & ltm);
                    if (p < CAP)
                        cand2[p] = ((ull)__float_as_uint(sv) << 32) | (k & 0xFFFFFFFFull);
                }
            }
        }
        __syncthreads();
    } else {
        // ---- exact fallback (rare): re-zero hist, full conf_pass histogram ----
        __syncthreads();
        for (int i = tid; i < NBINS; i += NT) hist[i] = 0;
        __syncthreads();
        {
            const float4* cls4 = (const float4*)cls;
            for (int q = tid; q < NA / 4; q += NT) {
                float4 v = cls4[q];
                unsigned int kx = make_key(v.x), ky = make_key(v.y);
                unsigned int kz = make_key(v.z), kw = make_key(v.w);
                if (kx) atomicAdd(&hist[min((kx - FB_KBASE) >> FB_SHIFT, (unsigned)(NBINS - 1))], 1u);
                if (ky) atomicAdd(&hist[min((ky - FB_KBASE) >> FB_SHIFT, (unsigned)(NBINS - 1))], 1u);
                if (kz) atomicAdd(&hist[min((kz - FB_KBASE) >> FB_SHIFT, (unsigned)(NBINS - 1))], 1u);
                if (kw) atomicAdd(&hist[min((kw - FB_KBASE) >> FB_SHIFT, (unsigned)(NBINS - 1))], 1u);
            }
        }
        __syncthreads();
        suffix_find(hist, wtot, TARGET, tid, &s_T1);
        {
            const ull thr = (s_T1 < 0) ? 0ull
                : ((ull)FB_KBASE + ((ull)(unsigned int)s_T1 << FB_SHIFT));
            const float4* cls4 = (const float4*)cls;
            for (int q = tid; q < NA / 4; q += NT) {
                float4 v = cls4[q];
                const unsigned int i0 = (unsigned int)q * 4u;
                float xs[4] = {v.x, v.y, v.z, v.w};
#pragma unroll
                for (int u = 0; u < 4; ++u) {
                    unsigned int d = make_key(xs[u]);
                    if (d && (ull)d >= thr) {
                        unsigned int p = atomicAdd(&s_cnt2, 1u);
                        if (p < CAP) {
                            float sv = sigmoidf(xs[u]);
                            cand2[p] = ((ull)__float_as_uint(sv) << 32) | (ull)(~(i0 + u));
                        }
                    }
                }
            }
        }
        __syncthreads();
    }

    const int F = min((int)s_cnt2, CAP);
    const int numSel = min(F, TOPK);

    // rank-by-counting (unique keys via ~idx) + FUSED box gather -> LDS.
    // Area computed here with the IDENTICAL fp expression as before (x2-x1 on
    // the stored values) -> bit-exact; removes the separate area pass+barrier.
    for (int e = tid; e < F; e += NT) {
        ull k = cand2[e];
        int rank = 0;
        int o = 0;
#pragma unroll 2
        for (; o + 4 <= F; o += 4) {
            ulonglong2 p0 = *(const ulonglong2*)&cand2[o];
            ulonglong2 p1 = *(const ulonglong2*)&cand2[o + 2];
            rank += (p0.x > k) + (p0.y > k) + (p1.x > k) + (p1.y > k);
        }
        for (; o < F; ++o) rank += (cand2[o] > k) ? 1 : 0;
        if (rank < TOPK) {
            unsigned int i = ~(unsigned int)(k & 0xFFFFFFFFull);
            float cx = box[i];
            float cy = box[NA + i];
            float w  = box[2 * NA + i];
            float h  = box[3 * NA + i];
            float hw = w * 0.5f, hh = h * 0.5f;
            float x1 = cx - hw, y1 = cy - hh, x2 = cx + hw, y2 = cy + hh;
            sBox[rank] = float4{x1, y1, x2, y2};
            sVal[rank] = __uint_as_float((unsigned int)(k >> 32));
            sAr[rank] = fmaxf(x2 - x1, 0.f) * fmaxf(y2 - y1, 0.f);
        }
    }
    __syncthreads();   // cand2 dead from here; pool becomes sSup

    // ---- suppression-mask build: rows striped across the 8 waves.
    // Zero-area rows (75% of rows for N(0,1) boxes) provably produce all-zero
    // words -> skip their IoU entirely (wave-uniform branch). ----
    float4 cb[5];
    float ca[5];
#pragma unroll
    for (int w = 0; w < 5; ++w) {
        int j = (w << 6) + lane;
        bool v = j < TOPK;
        cb[w] = v ? sBox[j] : float4{0.f, 0.f, 0.f, 0.f};
        ca[w] = v ? sAr[j] : 0.f;
    }
    for (int r = wave; r < TOPK; r += NW) {
        const bool vrow = r < numSel;      // wave-uniform
        float4 bi = sBox[r];
        float ai = sAr[r];
        const bool act = vrow && (ai > 0.0f);   // wave-uniform row skip
        const int w0 = r >> 6;             // words < w0 have all columns <= r
#pragma unroll
        for (int w = 0; w < 5; ++w) {
            ull bal = 0ull;
            if (w >= w0 && act) {          // uniform branch
                const int j = (w << 6) + lane;
                bool supb = false;
                if (j < numSel && j > r) {
                    float xx1 = fmaxf(bi.x, cb[w].x);
                    float yy1 = fmaxf(bi.y, cb[w].y);
                    float xx2 = fminf(bi.z, cb[w].z);
                    float yy2 = fminf(bi.w, cb[w].w);
                    float iw = fmaxf(xx2 - xx1, 0.0f);
                    float ih = fmaxf(yy2 - yy1, 0.0f);
                    float inter = iw * ih;
                    float un = ai + ca[w] - inter;
                    float D = fmaxf(un, 1e-9f);
                    supb = (double)inter > M45 * (double)D;  // == RN(inter/D) > 0.45f
                }
                bal = __ballot(supb);
            }
            if (lane == 0) sSup[r * 5 + w] = bal;
        }
    }
    __syncthreads();

    // ---- greedy scan (wave 0 only). Zero-skip: rows whose 5 mask words are
    // all zero contribute nothing to rem regardless of kept-status -> iterate
    // only set bits of nz (ballot of nonzero rows), in increasing row order.
    // Expected |nz| ~ tens, vs 300 dependent iterations before. ----
    if (wave != 0) return;

    ull rem0 = 0, rem1 = 0, rem2 = 0, rem3 = 0, rem4 = 0;
    {
        const ull* p = sSup + (size_t)lane * 5;
        ull B0 = p[0], B1 = p[1], B2 = p[2], B3 = p[3], B4 = p[4];
        PIN64(B0); PIN64(B1); PIN64(B2); PIN64(B3); PIN64(B4);
        ull nz = __ballot((B0 | B1 | B2 | B3 | B4) != 0ull);
        while (nz) {
            int i = __builtin_ctzll(nz);
            nz &= nz - 1;
            if (!((rem0 >> i) & 1ull)) {    // uniform: rem identical on all lanes
                rem0 |= readlane64(B0, i); rem1 |= readlane64(B1, i);
                rem2 |= readlane64(B2, i); rem3 |= readlane64(B3, i);
                rem4 |= readlane64(B4, i);
            }
        }
    }
    {
        const ull* p = sSup + (size_t)(64 + lane) * 5;
        ull B0 = p[0], B1 = p[1], B2 = p[2], B3 = p[3], B4 = p[4];
        PIN64(B0); PIN64(B1); PIN64(B2); PIN64(B3); PIN64(B4);
        ull nz = __ballot((B0 | B1 | B2 | B3 | B4) != 0ull);
        while (nz) {
            int i = __builtin_ctzll(nz);
            nz &= nz - 1;
            if (!((rem1 >> i) & 1ull)) {
                rem0 |= readlane64(B0, i); rem1 |= readlane64(B1, i);
                rem2 |= readlane64(B2, i); rem3 |= readlane64(B3, i);
                rem4 |= readlane64(B4, i);
            }
        }
    }
    {
        const ull* p = sSup + (size_t)(128 + lane) * 5;
        ull B0 = p[0], B1 = p[1], B2 = p[2], B3 = p[3], B4 = p[4];
        PIN64(B0); PIN64(B1); PIN64(B2); PIN64(B3); PIN64(B4);
        ull nz = __ballot((B0 | B1 | B2 | B3 | B4) != 0ull);
        while (nz) {
            int i = __builtin_ctzll(nz);
            nz &= nz - 1;
            if (!((rem2 >> i) & 1ull)) {
                rem0 |= readlane64(B0, i); rem1 |= readlane64(B1, i);
                rem2 |= readlane64(B2, i); rem3 |= readlane64(B3, i);
                rem4 |= readlane64(B4, i);
            }
        }
    }
    {
        const ull* p = sSup + (size_t)(192 + lane) * 5;
        ull B0 = p[0], B1 = p[1], B2 = p[2], B3 = p[3], B4 = p[4];
        PIN64(B0); PIN64(B1); PIN64(B2); PIN64(B3); PIN64(B4);
        ull nz = __ballot((B0 | B1 | B2 | B3 | B4) != 0ull);
        while (nz) {
            int i = __builtin_ctzll(nz);
            nz &= nz - 1;
            if (!((rem3 >> i) & 1ull)) {
                rem0 |= readlane64(B0, i); rem1 |= readlane64(B1, i);
                rem2 |= readlane64(B2, i); rem3 |= readlane64(B3, i);
                rem4 |= readlane64(B4, i);
            }
        }
    }
    {
        const bool v4 = lane < (TOPK - 256);
        const ull* p = sSup + (size_t)(256 + (v4 ? lane : 0)) * 5;
        ull B0 = v4 ? p[0] : 0ull, B1 = v4 ? p[1] : 0ull, B2 = v4 ? p[2] : 0ull,
            B3 = v4 ? p[3] : 0ull, B4 = v4 ? p[4] : 0ull;
        PIN64(B0); PIN64(B1); PIN64(B2); PIN64(B3); PIN64(B4);
        ull nz = __ballot((B0 | B1 | B2 | B3 | B4) != 0ull);
        while (nz) {
            int i = __builtin_ctzll(nz);
            nz &= nz - 1;
            if (!((rem4 >> i) & 1ull)) {
                rem0 |= readlane64(B0, i); rem1 |= readlane64(B1, i);
                rem2 |= readlane64(B2, i); rem3 |= readlane64(B3, i);
                rem4 |= readlane64(B4, i);
            }
        }
    }

    float* outp = out + ((size_t)b * NC + c) * (TOPK * 6);
    auto write_row = [&](int w, ull remw) {
        int r = (w << 6) + lane;
        if (r < TOPK) {
            float x1 = 0.f, y1 = 0.f, x2 = 0.f, y2 = 0.f, vv = 0.f, cc = 0.f;
            if (r < numSel && ((~remw >> lane) & 1ull)) {
                float4 bb = sBox[r];
                x1 = bb.x; y1 = bb.y; x2 = bb.z; y2 = bb.w;
                vv = sVal[r]; cc = (float)c;
            }
            float* row = outp + r * 6;
            *(float2*)(row)     = float2{x1, y1};
            *(float2*)(row + 2) = float2{x2, y2};
            *(float2*)(row + 4) = float2{vv, cc};
        }
    };
    write_row(0, rem0);
    write_row(1, rem1);
    write_row(2, rem2);
    write_row(3, rem3);
    write_row(4, rem4);
}

extern "C" void kernel_launch(void* const* d_in, const int* in_sizes, int n_in,
                              void* d_out, int out_size, void* d_ws, size_t ws_size,
                              hipStream_t stream) {
    const float* in = (const float*)d_in[0];
    float* out = (float*)d_out;
    (void)d_ws; (void)ws_size;   // fused kernel keeps all intermediates in LDS

    k_fused<<<NTASK, NT, 0, stream>>>(in, out);
}